// Round 10
// baseline (290.967 us; speedup 1.0000x reference)
//
#include <hip/hip_runtime.h>
#include <hip/hip_bf16.h>

// AttentionLayer, MFMA bf16 version.
// x (192,1024,128) f32; W_qkv (128,384) f32; W_out (128,128) f32; b_out (128) f32.
// out (192,1024,128) f32. H=8 heads x hd=16, N=SEQ=1024.
#define NBATCH 192
#define SEQ    1024
#define DIM    128
#define NH     8
#define EPS    1e-12f

typedef short bf16x8 __attribute__((ext_vector_type(8)));
typedef float f32x4  __attribute__((ext_vector_type(4)));

// ws layout: kvs 393216 f32 | kssum 24576 f32 | wsWT bf16 [4][2048 frags][8] | xb bf16 frags
#define KVS_F   393216
#define ZERO_F  417792
#define WSWT_OFF ((size_t)ZERO_F * 4)
#define XB_OFF   (WSWT_OFF + 131072)            // wsWT = 65536 shorts = 128 KB
#define XB_SHPB  32768                           // per-block xb shorts: 512 thr x 8 frags x 8
#define WS_NEED  (XB_OFF + (size_t)768 * XB_SHPB * 2)

static __device__ __forceinline__ unsigned short f2bf(float f) {
    unsigned u = __builtin_bit_cast(unsigned, f);
    u += 0x7fff + ((u >> 16) & 1);          // RTNE (cold paths only)
    return (unsigned short)(u >> 16);
}

// library bf16 converts — compiler emits the HW packed cvt correctly (m240).
// __hip_bfloat162 is not trivially copyable -> extract bits via memcpy (folds to reg move).
static __device__ __forceinline__ unsigned pk2(float a, float b) {
    __hip_bfloat162 h = __float22bfloat162_rn(make_float2(a, b));
    unsigned r;
    __builtin_memcpy(&r, &h, 4);
    return r;
}
static __device__ __forceinline__ unsigned short bf1(float a) {
    __hip_bfloat16 h = __float2bfloat16(a);
    unsigned short r;
    __builtin_memcpy(&r, &h, 2);
    return r;
}

template <int CTRL>
static __device__ __forceinline__ float dpp_add(float v) {
    int j = __builtin_amdgcn_mov_dpp(__builtin_bit_cast(int, v), CTRL, 0xf, 0xf, false);
    return v + __builtin_bit_cast(float, j);
}
// sum over the 16 lanes of a DPP row (= over n15); all lanes get the result
static __device__ __forceinline__ float r16sum(float v) {
    v = dpp_add<0xB1>(v);    // quad_perm [1,0,3,2]  : xor1
    v = dpp_add<0x4E>(v);    // quad_perm [2,3,0,1]  : xor2
    v = dpp_add<0x141>(v);   // row_half_mirror      : pairs 4-groups
    v = dpp_add<0x140>(v);   // row_mirror           : pairs 8-groups
    return v;
}

// strip: [row][32 els], granule(8 el)-swizzled by row&3. addr in shorts.
static __device__ __forceinline__ int strip_addr(int row, int el) {
    return row * 32 + ((((el >> 3) ^ (row & 3)) << 3) | (el & 7));
}

static __device__ __forceinline__ uint2 pack4(float a, float b, float c, float d) {
    uint2 r;
    r.x = pk2(a, b);
    r.y = pk2(c, d);
    return r;
}

static __device__ __forceinline__ bf16x8 cvt8(float4 a, float4 b) {
    uint4 u;
    u.x = pk2(a.x, a.y); u.y = pk2(a.z, a.w);
    u.z = pk2(b.x, b.y); u.w = pk2(b.z, b.w);
    return __builtin_bit_cast(bf16x8, u);
}

// B-frag direct from global, frag-major wsWT: frag id = ((ct*4+ks)*4+q)*16+n15,
// 8 consecutive shorts per lane -> wave reads 1 KB contiguous (L1/L2 resident).
static __device__ __forceinline__ bf16x8 gfrag(const unsigned short* __restrict__ wT,
                                               int ct, int ks, int lane) {
    return *reinterpret_cast<const bf16x8*>(wT + ((ct * 4 + ks) * 64 + lane) * 8);
}

// ---------------- k0: zero accumulators + convert weights into frag-major bf16 ----------------
__global__ __launch_bounds__(256) void k0_prep(const float* __restrict__ Wqkv,
                                               const float* __restrict__ Wout,
                                               float* __restrict__ zero_p,
                                               unsigned short* __restrict__ wsWT) {
    int bid = blockIdx.x, t = threadIdx.x;
    if (bid < 1632) { zero_p[bid * 256 + t] = 0.0f; return; }
    int i = (bid - 1632) * 256 + t;             // 0..65535, writes coalesced
    int which = i >> 14, e = i & 16383;
    int j = e & 7, f = e >> 3;
    int n15 = f & 15, q = (f >> 4) & 3, ks = (f >> 6) & 3, ct = f >> 8;
    int k = ks * 32 + q * 8 + j, n = ct * 16 + n15;
    float v = (which < 3) ? Wqkv[k * 384 + which * 128 + n] : Wout[k * 128 + n];
    wsWT[i] = f2bf(v);
}

// ---------------- k1: k,v GEMM -> normalize k -> kvs & ks_sum (+ xb handoff) ----------------
// LDS 80 KB (2 blocks/CU): redf 64K slab + strips 16K. (512,4). DYNAMIC ct loop (unroll 1)
// with SOFTWARE PIPELINE: next ct's kb/vb prefetched during the fold (loop-carried named
// arrays, static indices) -> weight-load latency hidden under fold VALU (r9 plateau theory).
__global__ __launch_bounds__(512, 4) void k1_kv(const float* __restrict__ x,
                                                const unsigned short* __restrict__ wsWT,
                                                float* __restrict__ kvs_ws,
                                                float* __restrict__ kssum_ws,
                                                unsigned short* __restrict__ xb,
                                                int writeXb) {
    __shared__ float redf[16384];               // 64 KB
    __shared__ unsigned short strips[8192];     // 16 KB
    int t = threadIdx.x, w = t >> 6, lane = t & 63, q = lane >> 4, n15 = lane & 15;
    int b = blockIdx.x >> 2, seg = blockIdx.x & 3;
    const unsigned short* wkT = wsWT + 16384;   // W_k frags
    const unsigned short* wvT = wsWT + 32768;   // W_v frags
    unsigned short* knS = strips + w * 1024;    // [16 m][32 l]
    unsigned short* vS  = knS + 512;            // [16 d][32 l]

    bf16x8 ah[2][4];
#pragma unroll
    for (int rs = 0; rs < 2; ++rs) {
        int row = seg * 256 + w * 32 + rs * 16 + n15;
        const float* xr = x + (size_t)(b * SEQ + row) * DIM;
#pragma unroll
        for (int ks = 0; ks < 4; ++ks) {
            float4 p0 = *reinterpret_cast<const float4*>(xr + ks * 32 + q * 8);
            float4 p1 = *reinterpret_cast<const float4*>(xr + ks * 32 + q * 8 + 4);
            ah[rs][ks] = cvt8(p0, p1);
        }
    }
    // xb handoff: store this thread's fragments so k2 skips the f32 read + conversion.
    if (writeXb) {
        unsigned short* xo = xb + (size_t)blockIdx.x * XB_SHPB + t * 8;
#pragma unroll
        for (int rs = 0; rs < 2; ++rs)
#pragma unroll
            for (int ks = 0; ks < 4; ++ks)
                *reinterpret_cast<uint4*>(xo + (rs * 4 + ks) * 4096) =
                    __builtin_bit_cast(uint4, ah[rs][ks]);
    }

    // pipeline prologue: ct=0 weight frags
    bf16x8 kb[4], vb[4];
#pragma unroll
    for (int ks = 0; ks < 4; ++ks) {
        kb[ks] = gfrag(wkT, 0, ks, lane);
        vb[ks] = gfrag(wvT, 0, ks, lane);
    }

#pragma unroll 1
    for (int ct = 0; ct < 8; ++ct) {
        f32x4 ka[2] = {(f32x4){0,0,0,0}, (f32x4){0,0,0,0}};
        f32x4 va[2] = {(f32x4){0,0,0,0}, (f32x4){0,0,0,0}};
#pragma unroll
        for (int ks = 0; ks < 4; ++ks)
#pragma unroll
            for (int rs = 0; rs < 2; ++rs) {
                ka[rs] = __builtin_amdgcn_mfma_f32_16x16x32_bf16(ah[rs][ks], kb[ks], ka[rs], 0, 0, 0);
                va[rs] = __builtin_amdgcn_mfma_f32_16x16x32_bf16(ah[rs][ks], vb[ks], va[rs], 0, 0, 0);
            }
        // prefetch next ct's frags — latency hidden under the fold below
        int cn = (ct + 1) & 7;
        bf16x8 nkb[4], nvb[4];
#pragma unroll
        for (int ks = 0; ks < 4; ++ks) {
            nkb[ks] = gfrag(wkT, cn, ks, lane);
            nvb[ks] = gfrag(wvT, cn, ks, lane);
        }

        float ksum = 0.f;
        // normalize k rows (reduce over n15 = head dim), stash kn & v into strips
#pragma unroll
        for (int rs = 0; rs < 2; ++rs) {
            float kn[4];
#pragma unroll
            for (int r = 0; r < 4; ++r) {
                float val = ka[rs][r];
                float ssq = r16sum(val * val);
                float di  = 1.0f / fmaxf(sqrtf(ssq), EPS);
                kn[r] = val * di;
                ksum += kn[r];
            }
            *reinterpret_cast<uint2*>(knS + strip_addr(n15, rs * 16 + q * 4)) =
                pack4(kn[0], kn[1], kn[2], kn[3]);
            *reinterpret_cast<uint2*>(vS + strip_addr(n15, rs * 16 + q * 4)) =
                pack4(va[rs][0], va[rs][1], va[rs][2], va[rs][3]);
        }
        // kvs[h][m][d] = kn^T (m x l=32) . v (l x d)  — one K=32 MFMA, retire to slab
        bf16x8 aK = *reinterpret_cast<const bf16x8*>(knS + strip_addr(n15, q * 8));
        bf16x8 bV = *reinterpret_cast<const bf16x8*>(vS + strip_addr(n15, q * 8));
        f32x4 kacc = __builtin_amdgcn_mfma_f32_16x16x32_bf16(aK, bV, (f32x4){0,0,0,0}, 0, 0, 0);
#pragma unroll
        for (int r = 0; r < 4; ++r)
            redf[w * 2048 + ct * 256 + (q * 4 + r) * 16 + n15] = kacc[r];
        // ks_sum: reduce over q-groups (rows), then atomics from lanes 0..15
        float s = ksum;
        s += __shfl_xor(s, 16); s += __shfl_xor(s, 32);
        if (lane < 16) atomicAdd(&kssum_ws[b * 128 + ct * 16 + n15], s);
        // rotate pipeline registers
#pragma unroll
        for (int ks = 0; ks < 4; ++ks) { kb[ks] = nkb[ks]; vb[ks] = nvb[ks]; }
    }

    // block-level kvs reduction over 8 waves, then one atomic per element
    __syncthreads();
#pragma unroll
    for (int i = 0; i < 4; ++i) {
        int el = i * 512 + t;
        float s = 0.f;
#pragma unroll
        for (int ww = 0; ww < 8; ++ww) s += redf[ww * 2048 + el];
        atomicAdd(&kvs_ws[b * 2048 + el], s);
    }
}

// ---------------- k2: per-rs { per-h {Q,V GEMM -> fold -> num MFMA -> half-tile} -> out proj } ----------------
// LDS 48 KB: kvsT 8K | strips 8K | half tile 32K. ONE __syncthreads (kvsT). (512,4).
// SOFTWARE PIPELINE on h-loop and out-proj ct-loop: next iteration's weight frags + kss/bout
// prefetched during the fold / stores (loop-carried named arrays, static indices). ah is
// per-rs (ahc, reloaded from xb each half) to pay the prefetch register bill: peak ~110 regs.
template <int XB>
__global__ __launch_bounds__(512, 4) void k2_out(const float* __restrict__ x,
                                                 const unsigned short* __restrict__ wsWT,
                                                 const float* __restrict__ kvs_ws,
                                                 const float* __restrict__ kssum_ws,
                                                 const float* __restrict__ bout,
                                                 float* __restrict__ out,
                                                 const unsigned short* __restrict__ xb) {
    __shared__ unsigned short lds[24576];       // 48 KB
    unsigned short* kvsT   = lds;               // [h*16+d][32 mpad] strip layout (8 KB)
    unsigned short* strips = lds + 4096;        // 8 waves x 512 shorts (8 KB)
    unsigned short* tile   = lds + 8192;        // 8 waves x (16 rows x 128 c) bf16 (32 KB)
    int t = threadIdx.x, w = t >> 6, lane = t & 63, q = lane >> 4, n15 = lane & 15;
    int b = blockIdx.x >> 2, seg = blockIdx.x & 3, rowbase = seg * 256;
    const unsigned short* wqT = wsWT;           // W_q frags
    const unsigned short* wvT = wsWT + 32768;   // W_v frags
    const unsigned short* woT = wsWT + 49152;   // W_out frags

    {   // build kvsT (bf16, transposed [h][d][m], m>=16 zero-padded)
        int row = t >> 2, part = t & 3, h = row >> 4, d = row & 15;
        unsigned es[8];
#pragma unroll
        for (int j = 0; j < 8; j += 2) {
            int m0 = part * 8 + j;
            float lo = (m0     < 16) ? kvs_ws[b * 2048 + h * 256 + m0 * 16 + d]       : 0.f;
            float hi = (m0 + 1 < 16) ? kvs_ws[b * 2048 + h * 256 + (m0 + 1) * 16 + d] : 0.f;
            es[j] = pk2(lo, hi);
        }
        uint4 v = {es[0], es[2], es[4], es[6]};
        *reinterpret_cast<uint4*>(kvsT + row * 32 + ((part ^ (row & 3)) << 3)) = v;
    }

    unsigned short* myS = strips + w * 512;     // per-wave 16x32 transpose strip
    unsigned short* tw  = tile + w * 2048;      // per-wave HALF tile (16 rows x 128 c)
    {   // zero qs-strip pad (els 16..31 of each of 16 rows) — K=32 MFMA zero padding
        uint2 z = {0, 0};
        *reinterpret_cast<uint2*>(myS + strip_addr(n15, 16 + q * 4)) = z;
    }
    __syncthreads();                            // kvsT ready

#pragma unroll 1
    for (int rs = 0; rs < 2; ++rs) {
        // per-rs A-fragments (frees 16 persistent regs vs ah[2][4])
        bf16x8 ahc[4];
        if (XB) {
            const unsigned short* xi = xb + (size_t)blockIdx.x * XB_SHPB + t * 8;
#pragma unroll
            for (int ks = 0; ks < 4; ++ks)
                ahc[ks] = *reinterpret_cast<const bf16x8*>(xi + (rs * 4 + ks) * 4096);
        } else {
            int row = rowbase + w * 32 + rs * 16 + n15;
            const float* xr = x + (size_t)(b * SEQ + row) * DIM;
#pragma unroll
            for (int ks = 0; ks < 4; ++ks) {
                float4 p0 = *reinterpret_cast<const float4*>(xr + ks * 32 + q * 8);
                float4 p1 = *reinterpret_cast<const float4*>(xr + ks * 32 + q * 8 + 4);
                ahc[ks] = cvt8(p0, p1);
            }
        }

        // pipeline prologue: h=0 frags + kss
        bf16x8 qb[4], vb[4];
#pragma unroll
        for (int ks = 0; ks < 4; ++ks) {
            qb[ks] = gfrag(wqT, 0, ks, lane);
            vb[ks] = gfrag(wvT, 0, ks, lane);
        }
        float kssh = kssum_ws[b * 128 + n15];

#pragma unroll 1
        for (int h = 0; h < 8; ++h) {
            f32x4 qa = (f32x4){0,0,0,0};
            f32x4 va = (f32x4){0,0,0,0};
#pragma unroll
            for (int ks = 0; ks < 4; ++ks) {
                qa = __builtin_amdgcn_mfma_f32_16x16x32_bf16(ahc[ks], qb[ks], qa, 0, 0, 0);
                va = __builtin_amdgcn_mfma_f32_16x16x32_bf16(ahc[ks], vb[ks], va, 0, 0, 0);
            }
            // prefetch next h's frags + kss — latency hidden under the fold below
            int hn = (h + 1) & 7;
            bf16x8 nqb[4], nvb[4];
#pragma unroll
            for (int ks = 0; ks < 4; ++ks) {
                nqb[ks] = gfrag(wqT, hn, ks, lane);
                nvb[ks] = gfrag(wvT, hn, ks, lane);
            }
            float nkss = kssum_ws[b * 128 + hn * 16 + n15];

            float pv[4];
#pragma unroll
            for (int r = 0; r < 4; ++r) {
                float val = qa[r];
                float ssq = r16sum(val * val);
                float tt  = r16sum(val * kssh);
                float di  = 1.0f / fmaxf(sqrtf(ssq), EPS);
                float inv = 1.0f / (tt * di + (float)SEQ);
                pv[r] = val * di * inv;                 // qs * inv
                va[r] *= (float)SEQ * inv;              // N * v * inv
            }
            // transpose qs into strip: rows q*4+r, col n15 (per-element — rows differ per r)
#pragma unroll
            for (int r = 0; r < 4; ++r)
                myS[strip_addr(q * 4 + r, n15)] = bf1(pv[r]);
            bf16x8 aq = *reinterpret_cast<const bf16x8*>(myS + strip_addr(n15, q * 8));
            bf16x8 bk = *reinterpret_cast<const bf16x8*>(kvsT + strip_addr(h * 16 + n15, q * 8));
            va = __builtin_amdgcn_mfma_f32_16x16x32_bf16(aq, bk, va, 0, 0, 0);   // = pre
#pragma unroll
            for (int r = 0; r < 4; ++r) {
                int rt = q * 4 + r;
                int colg = h * 2 + (n15 >> 3);
                tw[rt * 128 + (((colg ^ rt) << 3) | (n15 & 7))] = bf1(va[r]);
            }
            // rotate pipeline registers
#pragma unroll
            for (int ks = 0; ks < 4; ++ks) { qb[ks] = nqb[ks]; vb[ks] = nvb[ks]; }
            kssh = nkss;
        }

        // ---- out projection for this rs half (tile is wave-private: no barrier) ----
        bf16x8 ap[4];
#pragma unroll
        for (int ks = 0; ks < 4; ++ks)
            ap[ks] = *reinterpret_cast<const bf16x8*>(
                tw + n15 * 128 + ((((ks << 2) + q) ^ n15) << 3));
        bf16x8 bb[4];
#pragma unroll
        for (int ks = 0; ks < 4; ++ks) bb[ks] = gfrag(woT, 0, ks, lane);
        float bo = bout[n15];
#pragma unroll 1
        for (int ct = 0; ct < 8; ++ct) {
            f32x4 oa = (f32x4){0,0,0,0};
#pragma unroll
            for (int ks = 0; ks < 4; ++ks)
                oa = __builtin_amdgcn_mfma_f32_16x16x32_bf16(ap[ks], bb[ks], oa, 0, 0, 0);
            int cn = (ct + 1) & 7;
            bf16x8 nbb[4];
#pragma unroll
            for (int ks = 0; ks < 4; ++ks) nbb[ks] = gfrag(woT, cn, ks, lane);
            float nbo = bout[cn * 16 + n15];
#pragma unroll
            for (int r = 0; r < 4; ++r) {
                int row = rowbase + w * 32 + rs * 16 + q * 4 + r;
                out[(size_t)(b * SEQ + row) * DIM + ct * 16 + n15] = oa[r] + bo;
            }
#pragma unroll
            for (int ks = 0; ks < 4; ++ks) bb[ks] = nbb[ks];
            bo = nbo;
        }
    }
}

extern "C" void kernel_launch(void* const* d_in, const int* in_sizes, int n_in,
                              void* d_out, int out_size, void* d_ws, size_t ws_size,
                              hipStream_t stream) {
    const float* x    = (const float*)d_in[0];
    const float* Wqkv = (const float*)d_in[1];
    const float* Wout = (const float*)d_in[2];
    const float* bout = (const float*)d_in[3];
    float* out = (float*)d_out;

    float* kvs_ws   = (float*)d_ws;
    float* kssum_ws = kvs_ws + KVS_F;
    unsigned short* wsWT = (unsigned short*)((char*)d_ws + WSWT_OFF);
    unsigned short* xb   = (unsigned short*)((char*)d_ws + XB_OFF);
    int use_xb = (ws_size >= WS_NEED) ? 1 : 0;

    k0_prep<<<dim3(1888), dim3(256), 0, stream>>>(Wqkv, Wout, kvs_ws, wsWT);
    k1_kv<<<dim3(768), dim3(512), 0, stream>>>(x, wsWT, kvs_ws, kssum_ws, xb, use_xb);
    if (use_xb)
        k2_out<1><<<dim3(768), dim3(512), 0, stream>>>(x, wsWT, kvs_ws, kssum_ws, bout, out, xb);
    else
        k2_out<0><<<dim3(768), dim3(512), 0, stream>>>(x, wsWT, kvs_ws, kssum_ws, bout, out, xb);
}

// Round 11
// 281.537 us; speedup vs baseline: 1.0335x; 1.0335x over previous
//
#include <hip/hip_runtime.h>
#include <hip/hip_bf16.h>

// AttentionLayer, MFMA bf16 version.
// x (192,1024,128) f32; W_qkv (128,384) f32; W_out (128,128) f32; b_out (128) f32.
// out (192,1024,128) f32. H=8 heads x hd=16, N=SEQ=1024.
#define NBATCH 192
#define SEQ    1024
#define DIM    128
#define NH     8
#define EPS    1e-12f

typedef short bf16x8 __attribute__((ext_vector_type(8)));
typedef float f32x4  __attribute__((ext_vector_type(4)));

// ws layout: kvs_part[768][2048] f32 (per (b,seg) partials, no zeroing needed)
//          | kssum 24576 f32 (zeroed by k0, k1 atomics)
//          | wsWT bf16 [4][2048 frags][8]
#define KVSP_F   1572864
#define KSSUM_F  24576
#define WSWT_OFF ((size_t)(KVSP_F + KSSUM_F) * 4)

static __device__ __forceinline__ unsigned short f2bf(float f) {
    unsigned u = __builtin_bit_cast(unsigned, f);
    u += 0x7fff + ((u >> 16) & 1);          // RTNE (cold paths only)
    return (unsigned short)(u >> 16);
}

// library bf16 converts — compiler emits the HW packed cvt correctly (m240).
// __hip_bfloat162 is not trivially copyable -> extract bits via memcpy (folds to reg move).
static __device__ __forceinline__ unsigned pk2(float a, float b) {
    __hip_bfloat162 h = __float22bfloat162_rn(make_float2(a, b));
    unsigned r;
    __builtin_memcpy(&r, &h, 4);
    return r;
}
static __device__ __forceinline__ unsigned short bf1(float a) {
    __hip_bfloat16 h = __float2bfloat16(a);
    unsigned short r;
    __builtin_memcpy(&r, &h, 2);
    return r;
}

template <int CTRL>
static __device__ __forceinline__ float dpp_add(float v) {
    int j = __builtin_amdgcn_mov_dpp(__builtin_bit_cast(int, v), CTRL, 0xf, 0xf, false);
    return v + __builtin_bit_cast(float, j);
}
// sum over the 16 lanes of a DPP row (= over n15); all lanes get the result
static __device__ __forceinline__ float r16sum(float v) {
    v = dpp_add<0xB1>(v);    // quad_perm [1,0,3,2]  : xor1
    v = dpp_add<0x4E>(v);    // quad_perm [2,3,0,1]  : xor2
    v = dpp_add<0x141>(v);   // row_half_mirror      : pairs 4-groups
    v = dpp_add<0x140>(v);   // row_mirror           : pairs 8-groups
    return v;
}

// strip: [row][32 els], granule(8 el)-swizzled by row&3. addr in shorts.
static __device__ __forceinline__ int strip_addr(int row, int el) {
    return row * 32 + ((((el >> 3) ^ (row & 3)) << 3) | (el & 7));
}

static __device__ __forceinline__ uint2 pack4(float a, float b, float c, float d) {
    uint2 r;
    r.x = pk2(a, b);
    r.y = pk2(c, d);
    return r;
}

static __device__ __forceinline__ bf16x8 cvt8(float4 a, float4 b) {
    uint4 u;
    u.x = pk2(a.x, a.y); u.y = pk2(a.z, a.w);
    u.z = pk2(b.x, b.y); u.w = pk2(b.z, b.w);
    return __builtin_bit_cast(bf16x8, u);
}

// B-frag direct from global, frag-major wsWT: frag id = ((ct*4+ks)*4+q)*16+n15,
// 8 consecutive shorts per lane -> wave reads 1 KB contiguous (L1/L2 resident).
static __device__ __forceinline__ bf16x8 gfrag(const unsigned short* __restrict__ wT,
                                               int ct, int ks, int lane) {
    return *reinterpret_cast<const bf16x8*>(wT + ((ct * 4 + ks) * 64 + lane) * 8);
}

// ---------------- k0: convert weights to frag-major bf16 + zero kssum ----------------
__global__ __launch_bounds__(256) void k0_prep(const float* __restrict__ Wqkv,
                                               const float* __restrict__ Wout,
                                               float* __restrict__ kssum_ws,
                                               unsigned short* __restrict__ wsWT) {
    int i = blockIdx.x * 256 + threadIdx.x;     // 0..65535, writes coalesced
    if (i < KSSUM_F) kssum_ws[i] = 0.0f;        // k1 accumulates via atomics
    int which = i >> 14, e = i & 16383;
    int j = e & 7, f = e >> 3;
    int n15 = f & 15, q = (f >> 4) & 3, ks = (f >> 6) & 3, ct = f >> 8;
    int k = ks * 32 + q * 8 + j, n = ct * 16 + n15;
    float v = (which < 3) ? Wqkv[k * 384 + which * 128 + n] : Wout[k * 128 + n];
    wsWT[i] = f2bf(v);
}

// ---------------- k1: k,v GEMM -> normalize k -> kvs partial & ks_sum ----------------
// LDS 80 KB (2 blocks/CU): redf 64K slab + strips 16K. (512,4). DYNAMIC ct loop (unroll 1,
// r4/r9-proven: stops cross-iteration gfrag hoisting -> no spills). kvs retires to a per-
// (b,seg) PARTIAL via plain coalesced stores — no global atomics, no zeroing, no xb write.
__global__ __launch_bounds__(512, 4) void k1_kv(const float* __restrict__ x,
                                                const unsigned short* __restrict__ wsWT,
                                                float* __restrict__ kvs_part,
                                                float* __restrict__ kssum_ws) {
    __shared__ float redf[16384];               // 64 KB
    __shared__ unsigned short strips[8192];     // 16 KB
    int t = threadIdx.x, w = t >> 6, lane = t & 63, q = lane >> 4, n15 = lane & 15;
    int b = blockIdx.x >> 2, seg = blockIdx.x & 3;
    const unsigned short* wkT = wsWT + 16384;   // W_k frags
    const unsigned short* wvT = wsWT + 32768;   // W_v frags
    unsigned short* knS = strips + w * 1024;    // [16 m][32 l]
    unsigned short* vS  = knS + 512;            // [16 d][32 l]

    bf16x8 ah[2][4];
#pragma unroll
    for (int rs = 0; rs < 2; ++rs) {
        int row = seg * 256 + w * 32 + rs * 16 + n15;
        const float* xr = x + (size_t)(b * SEQ + row) * DIM;
#pragma unroll
        for (int ks = 0; ks < 4; ++ks) {
            float4 p0 = *reinterpret_cast<const float4*>(xr + ks * 32 + q * 8);
            float4 p1 = *reinterpret_cast<const float4*>(xr + ks * 32 + q * 8 + 4);
            ah[rs][ks] = cvt8(p0, p1);
        }
    }

#pragma unroll 1
    for (int ct = 0; ct < 8; ++ct) {
        f32x4 ka[2] = {(f32x4){0,0,0,0}, (f32x4){0,0,0,0}};
        f32x4 va[2] = {(f32x4){0,0,0,0}, (f32x4){0,0,0,0}};
#pragma unroll
        for (int ks = 0; ks < 4; ++ks) {
            bf16x8 kb = gfrag(wkT, ct, ks, lane);
            bf16x8 vb = gfrag(wvT, ct, ks, lane);
#pragma unroll
            for (int rs = 0; rs < 2; ++rs) {
                ka[rs] = __builtin_amdgcn_mfma_f32_16x16x32_bf16(ah[rs][ks], kb, ka[rs], 0, 0, 0);
                va[rs] = __builtin_amdgcn_mfma_f32_16x16x32_bf16(ah[rs][ks], vb, va[rs], 0, 0, 0);
            }
        }
        float ksum = 0.f;
        // normalize k rows (reduce over n15 = head dim), stash kn & v into strips
#pragma unroll
        for (int rs = 0; rs < 2; ++rs) {
            float kn[4];
#pragma unroll
            for (int r = 0; r < 4; ++r) {
                float val = ka[rs][r];
                float ssq = r16sum(val * val);
                float di  = 1.0f / fmaxf(sqrtf(ssq), EPS);
                kn[r] = val * di;
                ksum += kn[r];
            }
            *reinterpret_cast<uint2*>(knS + strip_addr(n15, rs * 16 + q * 4)) =
                pack4(kn[0], kn[1], kn[2], kn[3]);
            *reinterpret_cast<uint2*>(vS + strip_addr(n15, rs * 16 + q * 4)) =
                pack4(va[rs][0], va[rs][1], va[rs][2], va[rs][3]);
        }
        // kvs[h][m][d] = kn^T (m x l=32) . v (l x d)  — one K=32 MFMA, retire to slab
        bf16x8 aK = *reinterpret_cast<const bf16x8*>(knS + strip_addr(n15, q * 8));
        bf16x8 bV = *reinterpret_cast<const bf16x8*>(vS + strip_addr(n15, q * 8));
        f32x4 kacc = __builtin_amdgcn_mfma_f32_16x16x32_bf16(aK, bV, (f32x4){0,0,0,0}, 0, 0, 0);
#pragma unroll
        for (int r = 0; r < 4; ++r)
            redf[w * 2048 + ct * 256 + (q * 4 + r) * 16 + n15] = kacc[r];
        // ks_sum: reduce over q-groups (rows), then atomics from lanes 0..15
        float s = ksum;
        s += __shfl_xor(s, 16); s += __shfl_xor(s, 32);
        if (lane < 16) atomicAdd(&kssum_ws[b * 128 + ct * 16 + n15], s);
    }

    // block-level kvs reduction over 8 waves, then one PLAIN coalesced store per element
    __syncthreads();
    float* myPart = kvs_part + (size_t)blockIdx.x * 2048;   // blockIdx = b*4+seg
#pragma unroll
    for (int i = 0; i < 4; ++i) {
        int el = i * 512 + t;
        float s = 0.f;
#pragma unroll
        for (int ww = 0; ww < 8; ++ww) s += redf[ww * 2048 + el];
        myPart[el] = s;
    }
}

// ---------------- k2: per-rs { per-h {Q,V GEMM -> fold -> num MFMA -> half-tile} -> out proj } ----------------
// LDS 48 KB: kvsT 8K | strips 8K | half tile 32K. ONE __syncthreads (kvsT). (512,4).
// Minimal SWP (r10 autopsy: 80-reg pipeline spilled; this is 16): prefetch ONLY nqb+nkss
// under the fold; vb loads at iteration top (covered by the 4 qa MFMAs); out-proj r9-simple.
// ahc per-rs from f32 x (xb dropped: r4-vs-r9 showed input path ~free; saves k1 50 MB write).
__global__ __launch_bounds__(512, 4) void k2_out(const float* __restrict__ x,
                                                 const unsigned short* __restrict__ wsWT,
                                                 const float* __restrict__ kvs_part,
                                                 const float* __restrict__ kssum_ws,
                                                 const float* __restrict__ bout,
                                                 float* __restrict__ out) {
    __shared__ unsigned short lds[24576];       // 48 KB
    unsigned short* kvsT   = lds;               // [h*16+d][32 mpad] strip layout (8 KB)
    unsigned short* strips = lds + 4096;        // 8 waves x 512 shorts (8 KB)
    unsigned short* tile   = lds + 8192;        // 8 waves x (16 rows x 128 c) bf16 (32 KB)
    int t = threadIdx.x, w = t >> 6, lane = t & 63, q = lane >> 4, n15 = lane & 15;
    int b = blockIdx.x >> 2, seg = blockIdx.x & 3, rowbase = seg * 256;
    const unsigned short* wqT = wsWT;           // W_q frags
    const unsigned short* wvT = wsWT + 32768;   // W_v frags
    const unsigned short* woT = wsWT + 49152;   // W_out frags

    {   // build kvsT (bf16, transposed [h][d][m], m>=16 zero-padded) from 4 seg partials
        int row = t >> 2, part = t & 3, h = row >> 4, d = row & 15;
        const float* kp = kvs_part + (size_t)b * 4 * 2048;
        unsigned es[8];
#pragma unroll
        for (int j = 0; j < 8; j += 2) {
            int m0 = part * 8 + j;
            float lo = 0.f, hi = 0.f;
#pragma unroll
            for (int s = 0; s < 4; ++s) {
                if (m0     < 16) lo += kp[s * 2048 + h * 256 + m0 * 16 + d];
                if (m0 + 1 < 16) hi += kp[s * 2048 + h * 256 + (m0 + 1) * 16 + d];
            }
            es[j] = pk2(lo, hi);
        }
        uint4 v = {es[0], es[2], es[4], es[6]};
        *reinterpret_cast<uint4*>(kvsT + row * 32 + ((part ^ (row & 3)) << 3)) = v;
    }

    unsigned short* myS = strips + w * 512;     // per-wave 16x32 transpose strip
    unsigned short* tw  = tile + w * 2048;      // per-wave HALF tile (16 rows x 128 c)
    {   // zero qs-strip pad (els 16..31 of each of 16 rows) — K=32 MFMA zero padding
        uint2 z = {0, 0};
        *reinterpret_cast<uint2*>(myS + strip_addr(n15, 16 + q * 4)) = z;
    }
    __syncthreads();                            // kvsT ready

    // qb pipeline spans both rs halves (wq frags are rs-independent; hn wraps 7->0)
    bf16x8 qb[4];
#pragma unroll
    for (int ks = 0; ks < 4; ++ks) qb[ks] = gfrag(wqT, 0, ks, lane);
    float kssh = kssum_ws[b * 128 + n15];

#pragma unroll 1
    for (int rs = 0; rs < 2; ++rs) {
        // per-rs A-fragments from f32 x
        bf16x8 ahc[4];
        {
            int row = rowbase + w * 32 + rs * 16 + n15;
            const float* xr = x + (size_t)(b * SEQ + row) * DIM;
#pragma unroll
            for (int ks = 0; ks < 4; ++ks) {
                float4 p0 = *reinterpret_cast<const float4*>(xr + ks * 32 + q * 8);
                float4 p1 = *reinterpret_cast<const float4*>(xr + ks * 32 + q * 8 + 4);
                ahc[ks] = cvt8(p0, p1);
            }
        }

        // ---- per-h: Q,V head-GEMMs -> fold norms -> numerator MFMA -> retire into half tile ----
#pragma unroll 1
        for (int h = 0; h < 8; ++h) {
            // vb at top: latency partially covered by the 4 qa MFMAs below
            bf16x8 vb0 = gfrag(wvT, h, 0, lane);
            bf16x8 vb1 = gfrag(wvT, h, 1, lane);
            bf16x8 vb2 = gfrag(wvT, h, 2, lane);
            bf16x8 vb3 = gfrag(wvT, h, 3, lane);
            f32x4 qa = (f32x4){0,0,0,0};
            qa = __builtin_amdgcn_mfma_f32_16x16x32_bf16(ahc[0], qb[0], qa, 0, 0, 0);
            qa = __builtin_amdgcn_mfma_f32_16x16x32_bf16(ahc[1], qb[1], qa, 0, 0, 0);
            qa = __builtin_amdgcn_mfma_f32_16x16x32_bf16(ahc[2], qb[2], qa, 0, 0, 0);
            qa = __builtin_amdgcn_mfma_f32_16x16x32_bf16(ahc[3], qb[3], qa, 0, 0, 0);
            f32x4 va = (f32x4){0,0,0,0};
            va = __builtin_amdgcn_mfma_f32_16x16x32_bf16(ahc[0], vb0, va, 0, 0, 0);
            va = __builtin_amdgcn_mfma_f32_16x16x32_bf16(ahc[1], vb1, va, 0, 0, 0);
            va = __builtin_amdgcn_mfma_f32_16x16x32_bf16(ahc[2], vb2, va, 0, 0, 0);
            va = __builtin_amdgcn_mfma_f32_16x16x32_bf16(ahc[3], vb3, va, 0, 0, 0);

            // prefetch next h's qb + kss — 16+1 regs, latency hidden under the fold
            int hn = (h + 1) & 7;
            bf16x8 nqb0 = gfrag(wqT, hn, 0, lane);
            bf16x8 nqb1 = gfrag(wqT, hn, 1, lane);
            bf16x8 nqb2 = gfrag(wqT, hn, 2, lane);
            bf16x8 nqb3 = gfrag(wqT, hn, 3, lane);
            float nkss = kssum_ws[b * 128 + hn * 16 + n15];

            float pv[4];
#pragma unroll
            for (int r = 0; r < 4; ++r) {
                float val = qa[r];
                float ssq = r16sum(val * val);
                float tt  = r16sum(val * kssh);
                float di  = 1.0f / fmaxf(sqrtf(ssq), EPS);
                float inv = 1.0f / (tt * di + (float)SEQ);
                pv[r] = val * di * inv;                 // qs * inv
                va[r] *= (float)SEQ * inv;              // N * v * inv
            }
            // transpose qs into strip: rows q*4+r, col n15 (per-element — rows differ per r)
#pragma unroll
            for (int r = 0; r < 4; ++r)
                myS[strip_addr(q * 4 + r, n15)] = bf1(pv[r]);
            bf16x8 aq = *reinterpret_cast<const bf16x8*>(myS + strip_addr(n15, q * 8));
            bf16x8 bk = *reinterpret_cast<const bf16x8*>(kvsT + strip_addr(h * 16 + n15, q * 8));
            va = __builtin_amdgcn_mfma_f32_16x16x32_bf16(aq, bk, va, 0, 0, 0);   // = pre
#pragma unroll
            for (int r = 0; r < 4; ++r) {
                int rt = q * 4 + r;
                int colg = h * 2 + (n15 >> 3);
                tw[rt * 128 + (((colg ^ rt) << 3) | (n15 & 7))] = bf1(va[r]);
            }
            // rotate pipeline
            qb[0] = nqb0; qb[1] = nqb1; qb[2] = nqb2; qb[3] = nqb3;
            kssh = nkss;
        }

        // ---- out projection for this rs half (tile is wave-private: no barrier), r9-simple ----
        bf16x8 ap[4];
#pragma unroll
        for (int ks = 0; ks < 4; ++ks)
            ap[ks] = *reinterpret_cast<const bf16x8*>(
                tw + n15 * 128 + ((((ks << 2) + q) ^ n15) << 3));
#pragma unroll 1
        for (int ct = 0; ct < 8; ++ct) {
            f32x4 oa = (f32x4){0,0,0,0};
#pragma unroll
            for (int ks = 0; ks < 4; ++ks) {
                bf16x8 bb = gfrag(woT, ct, ks, lane);
                oa = __builtin_amdgcn_mfma_f32_16x16x32_bf16(ap[ks], bb, oa, 0, 0, 0);
            }
            float bo = bout[ct * 16 + n15];
#pragma unroll
            for (int r = 0; r < 4; ++r) {
                int row = rowbase + w * 32 + rs * 16 + q * 4 + r;
                out[(size_t)(b * SEQ + row) * DIM + ct * 16 + n15] = oa[r] + bo;
            }
        }
    }
}

extern "C" void kernel_launch(void* const* d_in, const int* in_sizes, int n_in,
                              void* d_out, int out_size, void* d_ws, size_t ws_size,
                              hipStream_t stream) {
    const float* x    = (const float*)d_in[0];
    const float* Wqkv = (const float*)d_in[1];
    const float* Wout = (const float*)d_in[2];
    const float* bout = (const float*)d_in[3];
    float* out = (float*)d_out;

    float* kvs_part = (float*)d_ws;
    float* kssum_ws = kvs_part + KVSP_F;
    unsigned short* wsWT = (unsigned short*)((char*)d_ws + WSWT_OFF);

    k0_prep<<<dim3(256), dim3(256), 0, stream>>>(Wqkv, Wout, kssum_ws, wsWT);
    k1_kv<<<dim3(768), dim3(512), 0, stream>>>(x, wsWT, kvs_part, kssum_ws);
    k2_out<<<dim3(768), dim3(512), 0, stream>>>(x, wsWT, kvs_part, kssum_ws, bout, out);
}